// Round 11
// baseline (149.738 us; speedup 1.0000x reference)
//
#include <hip/hip_runtime.h>

#define N_PTS    20000
#define M_NODES  1024
#define BATCH    4
#define NNODE    (BATCH * M_NODES)   // 4096
#define K_NN     50
#define D_MODEL  256
#define NPF      84
#define CAP      768                 // ws candidate capacity per node
#define SELWIN   160                 // refine target window upper bound
#define NSMP     2048                // samples for threshold
#define WLO      12                  // sample-count window (of 2048 samples)
#define WHI      24
// kernel B tiling
#define TN        32                 // nodes per block
#define KB_PPT    8                  // points per thread (contiguous)
#define KB_CHUNK  2048               // 256*8 points per chunk-block
#define KB_NCHUNK 10                 // 10*2048 = 20480 >= 20000

__device__ __forceinline__ float signed_angle(float ax, float ay, float az,
                                              float bx, float by, float bz) {
    float cx = ay * bz - az * by;
    float cy = az * bx - ax * bz;
    float cz = ax * by - ay * bx;
    float s = sqrtf(cx * cx + cy * cy + cz * cz);
    float c = ax * bx + ay * by + az * bz;
    float a = atan2f(s, c);
    return (c < 0.0f) ? -a : a;
}

// ===== Kernel A: wave-per-node threshold from LDS-staged samples + pos_emb =====
__global__ __launch_bounds__(256) void ka_thresh(
    const float* __restrict__ points, const float* __restrict__ nodes,
    float* __restrict__ tws, int* __restrict__ gcount, float* __restrict__ out)
{
    __shared__ float s3[NSMP * 3];       // 24 KB staged sample points
    const int tid  = threadIdx.x;
    const int w    = tid >> 6;
    const int lane = tid & 63;
    const int bm   = blockIdx.x * 4 + w;
    const int b    = bm >> 10;
    const float* pts = points + (size_t)b * N_PTS * 3;

    {
        const float4* src = (const float4*)pts;
        float4* dst = (float4*)s3;
        #pragma unroll
        for (int k = 0; k < 6; ++k)
            dst[tid + 256 * k] = src[tid + 256 * k];
    }
    __syncthreads();

    const float nx = nodes[(size_t)bm * 3 + 0];
    const float ny = nodes[(size_t)bm * 3 + 1];
    const float nz = nodes[(size_t)bm * 3 + 2];

    unsigned short keys[32];
    #pragma unroll
    for (int s = 0; s < 32; ++s) {
        int j = lane + 64 * s;
        float dx = s3[3 * j + 0] - nx;
        float dy = s3[3 * j + 1] - ny;
        float dz = s3[3 * j + 2] - nz;
        float d2 = dx * dx + dy * dy + dz * dz;
        keys[s] = (unsigned short)(__float_as_uint(d2) >> 16);
    }

    unsigned lo = 0, hi = 0x7F81u, v = 0;
    for (int it = 0; it < 16; ++it) {
        unsigned mid = lo + ((hi - lo) >> 1);
        int c = 0;
        #pragma unroll
        for (int s = 0; s < 32; ++s) c += (int)((unsigned)keys[s] < mid);
        for (int off = 32; off; off >>= 1) c += __shfl_down(c, off);
        c = __shfl(c, 0);
        if (c >= WLO && c <= WHI) { v = mid; break; }
        if (c < WLO) lo = mid; else hi = mid;
        if (hi - lo <= 1u) break;
    }
    if (v == 0) v = hi;
    if (lane == 0) { tws[bm] = __uint_as_float(v << 16); gcount[bm] = 0; }

    #pragma unroll
    for (int r = 0; r < 4; ++r) {
        int d = lane + 64 * r;
        float pv = 0.0f;
        if (d < 3 * NPF) {
            int c2 = d / NPF, rr = d - c2 * NPF, i = rr >> 1;
            float nc = (c2 == 0) ? nx : ((c2 == 1) ? ny : nz);
            const float L2_10000 = 13.287712379549449f;
            float tinv = exp2f(-L2_10000 * (float)i / 42.0f);
            float x = nc * tinv;
            pv = (rr & 1) ? cosf(x) : sinf(x);
        }
        out[(size_t)NNODE * D_MODEL + (size_t)bm * D_MODEL + d] = pv;
    }
}

// ===== Kernel B: mask-matrix scan + wave compaction (no LDS atomics) =====
__global__ __launch_bounds__(256) void kb_scan(
    const float* __restrict__ points, const float* __restrict__ nodes,
    const float* __restrict__ tws, int* __restrict__ gcount,
    unsigned short* __restrict__ cand)
{
    __shared__ unsigned char smask[TN][256];   // 8 KB survivor masks

    const int tile = blockIdx.x;          // 0..127
    const int ch   = blockIdx.y;          // 0..9
    const int ngb  = tile * TN;
    const int b    = ngb >> 10;
    const int tid  = threadIdx.x;
    const float* pts = points + (size_t)b * N_PTS * 3;

    // 8 contiguous points per thread; N_PTS % 8 == 0 -> all-or-nothing per thread
    const int j0 = ch * KB_CHUNK + tid * KB_PPT;
    float px[KB_PPT], py[KB_PPT], pz[KB_PPT], pp[KB_PPT];
    if (j0 < N_PTS) {
        const float4* s4 = (const float4*)(pts + (size_t)j0 * 3);
        float4 v0 = s4[0], v1 = s4[1], v2 = s4[2], v3 = s4[3], v4 = s4[4], v5 = s4[5];
        px[0]=v0.x; py[0]=v0.y; pz[0]=v0.z;
        px[1]=v0.w; py[1]=v1.x; pz[1]=v1.y;
        px[2]=v1.z; py[2]=v1.w; pz[2]=v2.x;
        px[3]=v2.y; py[3]=v2.z; pz[3]=v2.w;
        px[4]=v3.x; py[4]=v3.y; pz[4]=v3.z;
        px[5]=v3.w; py[5]=v4.x; pz[5]=v4.y;
        px[6]=v4.z; py[6]=v4.w; pz[6]=v5.x;
        px[7]=v5.y; py[7]=v5.z; pz[7]=v5.w;
    } else {
        #pragma unroll
        for (int p = 0; p < KB_PPT; ++p) { px[p]=1e18f; py[p]=1e18f; pz[p]=1e18f; }
    }
    #pragma unroll
    for (int p = 0; p < KB_PPT; ++p)
        pp[p] = px[p]*px[p] + py[p]*py[p] + pz[p]*pz[p];

    // Phase 1: masks for all 32 nodes (4-node register groups)
    for (int n0 = 0; n0 < TN; n0 += 4) {
        float ax[4], ay[4], az[4], rhs[4];
        #pragma unroll
        for (int g = 0; g < 4; ++g) {
            int ng = ngb + n0 + g;                       // block-uniform -> s_load
            float nx = nodes[ng * 3 + 0];
            float ny = nodes[ng * 3 + 1];
            float nz = nodes[ng * 3 + 2];
            float t  = tws[ng];
            ax[g] = -2.0f * nx; ay[g] = -2.0f * ny; az[g] = -2.0f * nz;
            // conservative margin >> fma-contraction rounding; kc re-ranks exactly
            rhs[g] = t * 1.0001f + 3e-5f - (nx*nx + ny*ny + nz*nz);
        }
        unsigned msk[4] = {0u, 0u, 0u, 0u};
        #pragma unroll
        for (int p = 0; p < KB_PPT; ++p) {
            #pragma unroll
            for (int g = 0; g < 4; ++g) {
                float s = fmaf(px[p], ax[g], fmaf(py[p], ay[g], fmaf(pz[p], az[g], pp[p])));
                msk[g] |= (s < rhs[g]) ? (1u << p) : 0u;
            }
        }
        #pragma unroll
        for (int g = 0; g < 4; ++g)
            smask[n0 + g][tid] = (unsigned char)msk[g];
    }
    __syncthreads();

    // Phase 2: wave wv compacts its 8 nodes (one global atomic per node)
    const int wv = tid >> 6, lane = tid & 63;
    #pragma unroll
    for (int nn2 = 0; nn2 < TN / 4; ++nn2) {
        int n = wv * (TN / 4) + nn2;
        unsigned long long wmask = 0;
        if (lane < 32) wmask = ((const unsigned long long*)smask[n])[lane];
        int c = (int)__popcll(wmask);
        int inc = c;
        #pragma unroll
        for (int s = 1; s < 32; s <<= 1) {
            int u = __shfl_up(inc, s);
            if (lane >= s) inc += u;
        }
        int total = __shfl(inc, 31);
        if (total == 0) continue;
        int basep = 0;
        if (lane == 0) basep = atomicAdd(&gcount[ngb + n], total);
        basep = __shfl(basep, 0);
        int pos = basep + inc - c;
        while (wmask) {
            int bit = (int)__builtin_ctzll(wmask);
            wmask &= wmask - 1;
            if (pos < CAP)
                cand[(size_t)(ngb + n) * CAP + pos] =
                    (unsigned short)(ch * KB_CHUNK + lane * 64 + bit);
            ++pos;
        }
    }
}

// ===== Kernel C: wave-per-node exact top-50 + PPF features + projection =====
__global__ __launch_bounds__(256) void kc_select(
    const float* __restrict__ points, const float* __restrict__ nodes,
    const float* __restrict__ pnrm, const float* __restrict__ nnrm,
    const float* __restrict__ W, const float* __restrict__ bias,
    const float* __restrict__ tws, const int* __restrict__ gcount,
    const unsigned short* __restrict__ cand, float* __restrict__ out)
{
    __shared__ unsigned long long skeys[4][CAP];   // 24.6 KB
    __shared__ float4 f4v[4][K_NN];
    __shared__ unsigned short selidx[4][K_NN];

    const int tid  = threadIdx.x;
    const int wv   = tid >> 6;
    const int lane = tid & 63;
    const int bm   = blockIdx.x * 4 + wv;
    const int b    = bm >> 10;
    const float* pts = points + (size_t)b * N_PTS * 3;
    const float* pnr = pnrm   + (size_t)b * N_PTS * 3;
    const float nx  = nodes[(size_t)bm * 3 + 0];
    const float ny  = nodes[(size_t)bm * 3 + 1];
    const float nz  = nodes[(size_t)bm * 3 + 2];
    const float n1x = nnrm[(size_t)bm * 3 + 0];
    const float n1y = nnrm[(size_t)bm * 3 + 1];
    const float n1z = nnrm[(size_t)bm * 3 + 2];

    auto d2bits = [&](int i) -> unsigned int {
        float dx = pts[i * 3 + 0] - nx;
        float dy = pts[i * 3 + 1] - ny;
        float dz = pts[i * 3 + 2] - nz;
        return __float_as_uint(dx * dx + dy * dy + dz * dz);
    };

    if (lane < K_NN) selidx[wv][lane] = 0;   // defense vs pathological ties

    const unsigned long long INVALID = ~0ull;
    int cnt = gcount[bm];
    int nsel = 0;

    if (cnt >= K_NN && cnt <= CAP) {
        // ---- fast path: candidate keys in registers, ballot-count refine ----
        const unsigned short* cp = cand + (size_t)bm * CAP;
        unsigned long long key[12];
        #pragma unroll
        for (int r = 0; r < 12; ++r) {
            int s = r * 64 + lane;
            key[r] = INVALID;
            if (s < cnt) {
                int i = (int)cp[s];
                key[r] = ((unsigned long long)d2bits(i) << 32) | (unsigned int)i;
            }
        }

        unsigned long long tcut = INVALID;   // take-all if cnt small or no converge
        bool conv = (cnt <= SELWIN);
        if (!conv) {
            unsigned lo = 0, hi = __float_as_uint(tws[bm]);
            for (int it = 0; it < 32 && !conv; ++it) {
                unsigned mid = lo + ((hi - lo) >> 1);
                unsigned long long tm = (unsigned long long)mid << 32;
                int c = 0;
                #pragma unroll
                for (int r = 0; r < 12; ++r)
                    c += (int)__popcll(__ballot(key[r] < tm));
                if (c >= K_NN && c <= SELWIN) { tcut = tm; conv = true; }
                else if (c < K_NN) lo = mid;
                else hi = mid;
                if (hi - lo <= 1u) break;
            }
        }

        int run = 0;
        #pragma unroll
        for (int r = 0; r < 12; ++r) {
            bool p = key[r] < tcut;
            unsigned long long mask = __ballot(p);
            if (p) {
                int q = run + (int)__popcll(mask & ((1ull << lane) - 1ull));
                skeys[wv][q] = key[r];
            }
            run += (int)__popcll(mask);
        }
        nsel = run;
    } else {
        // ---- slow path (rare): wave-local global repair ----
        unsigned tb = __float_as_uint(tws[bm]);
        unsigned lo = 0, hi = 0x7F000000u, good = 0;
        bool haveLo = false, haveHi = false;
        if (cnt < K_NN) { lo = tb; haveLo = true; }
        else            { hi = tb; haveHi = true; }
        unsigned cur = tb;
        for (int a = 0; a < 40 && !good; ++a) {
            if (haveLo && !haveHi) {
                cur = (cur < 0x7E800000u) ? cur + 0x00800000u : 0x7F000000u;
            } else if (haveHi && !haveLo) {
                cur = (cur >= 0x00800000u) ? cur - 0x00800000u : (cur >> 1);
            } else {
                cur = lo + ((hi - lo) >> 1);
                if (hi - lo <= 1u) { good = hi; break; }
            }
            float tf = __uint_as_float(cur);
            int c = 0;
            for (int i0 = lane; i0 < N_PTS; i0 += 64) {
                float dx = pts[i0 * 3 + 0] - nx;
                float dy = pts[i0 * 3 + 1] - ny;
                float dz = pts[i0 * 3 + 2] - nz;
                c += (int)(dx * dx + dy * dy + dz * dz < tf);
            }
            for (int off = 32; off; off >>= 1) c += __shfl_down(c, off);
            c = __shfl(c, 0);
            if (c >= K_NN && c <= CAP) good = cur;
            else if (c < K_NN) { lo = cur; haveLo = true; }
            else               { hi = cur; haveHi = true; }
        }
        if (!good) good = haveHi ? hi : 0x7F000000u;
        int run = 0;
        for (int base = 0; base < N_PTS; base += 64) {
            int i0 = base + lane;
            bool pred = false;
            unsigned kb2 = 0;
            if (i0 < N_PTS) { kb2 = d2bits(i0); pred = kb2 < good; }
            unsigned long long mask = __ballot(pred);
            if (pred) {
                int q = run + (int)__popcll(mask & ((1ull << lane) - 1ull));
                if (q < CAP)
                    skeys[wv][q] = ((unsigned long long)kb2 << 32) | (unsigned int)i0;
            }
            run += (int)__popcll(mask);
        }
        nsel = run < CAP ? run : CAP;
    }
    __syncthreads();

    // ---- exact rank selection of the 50 nearest (ties -> low idx) ----
    for (int s = lane; s < nsel; s += 64) {
        unsigned long long mk = skeys[wv][s];
        int rank = 0;
        for (int j = 0; j < nsel; ++j) rank += (int)(skeys[wv][j] < mk);
        if (rank < K_NN) selidx[wv][rank] = (unsigned short)mk;  // idx < 65536
    }
    __syncthreads();

    // ---- PPF features (one neighbor per lane) ----
    if (lane < K_NN) {
        int i = (int)selidx[wv][lane];
        float pxx = pts[i * 3 + 0], pyy = pts[i * 3 + 1], pzz = pts[i * 3 + 2];
        float qx = pnr[i * 3 + 0], qy = pnr[i * 3 + 1], qz = pnr[i * 3 + 2];
        float ijx = pxx - nx, ijy = pyy - ny, ijz = pzz - nz;
        float d = sqrtf(ijx * ijx + ijy * ijy + ijz * ijz);
        f4v[wv][lane] = make_float4(d,
                                    signed_angle(ijx, ijy, ijz, n1x, n1y, n1z),
                                    signed_angle(-ijx, -ijy, -ijz, qx, qy, qz),
                                    signed_angle(n1x, n1y, n1z, qx, qy, qz));
    }
    __syncthreads();

    // ---- glob[d] = max_k (f4[k] . W[:,d]) + b[d] ; 4 dims per lane ----
    {
        float w0[4], w1[4], w2[4], w3[4], bb[4], mx[4];
        #pragma unroll
        for (int q = 0; q < 4; ++q) {
            int d = lane + 64 * q;
            w0[q] = W[d]; w1[q] = W[D_MODEL + d];
            w2[q] = W[2 * D_MODEL + d]; w3[q] = W[3 * D_MODEL + d];
            bb[q] = bias[d]; mx[q] = -INFINITY;
        }
        #pragma unroll 5
        for (int k = 0; k < K_NN; ++k) {
            float4 f = f4v[wv][k];
            #pragma unroll
            for (int q = 0; q < 4; ++q)
                mx[q] = fmaxf(mx[q], f.x * w0[q] + f.y * w1[q] + f.z * w2[q] + f.w * w3[q]);
        }
        #pragma unroll
        for (int q = 0; q < 4; ++q)
            out[(size_t)bm * D_MODEL + lane + 64 * q] = mx[q] + bb[q];
    }
}

extern "C" void kernel_launch(void* const* d_in, const int* in_sizes, int n_in,
                              void* d_out, int out_size, void* d_ws, size_t ws_size,
                              hipStream_t stream) {
    const float* points = (const float*)d_in[0];
    const float* nodes  = (const float*)d_in[1];
    const float* pn     = (const float*)d_in[2];
    const float* nn     = (const float*)d_in[3];
    const float* W      = (const float*)d_in[4];
    const float* bias   = (const float*)d_in[5];
    float* out = (float*)d_out;

    // ws layout: tws f32[4096] @0 ; gcount i32[4096] @16K ; cand u16[4096*768] @32K
    char* ws = (char*)d_ws;
    float* tws = (float*)ws;
    int* gcount = (int*)(ws + 16384);
    unsigned short* cand = (unsigned short*)(ws + 32768);

    ka_thresh<<<dim3(NNODE / 4), dim3(256), 0, stream>>>(points, nodes, tws, gcount, out);
    kb_scan<<<dim3(NNODE / TN, KB_NCHUNK), dim3(256), 0, stream>>>(points, nodes, tws, gcount, cand);
    kc_select<<<dim3(NNODE / 4), dim3(256), 0, stream>>>(points, nodes, pn, nn, W, bias,
                                                         tws, gcount, cand, out);
}

// Round 12
// 74.437 us; speedup vs baseline: 2.0116x; 2.0116x over previous
//
#include <hip/hip_runtime.h>

#define N_PTS    20000
#define M_NODES  1024
#define BATCH    4
#define NNODE    (BATCH * M_NODES)   // 4096
#define K_NN     50
#define D_MODEL  256
#define NPF      84
#define CAP      768                 // ws candidate capacity per node
#define SELWIN   160                 // refine target window upper bound
#define NSMP     2048                // samples for threshold
#define WLO      26                  // sample-count window (of 2048 samples)
#define WHI      50                  // [26,50]: P(survivors<50) ~ 1e-5 (r11 lesson)
// kernel B tiling
#define TN        32                 // nodes per block
#define KB_PPT    8                  // points per thread (contiguous)
#define KB_CHUNK  2048               // 256*8 points per chunk-block
#define KB_NCHUNK 10                 // 10*2048 = 20480 >= 20000

__device__ __forceinline__ float signed_angle(float ax, float ay, float az,
                                              float bx, float by, float bz) {
    float cx = ay * bz - az * by;
    float cy = az * bx - ax * bz;
    float cz = ax * by - ay * bx;
    float s = sqrtf(cx * cx + cy * cy + cz * cz);
    float c = ax * bx + ay * by + az * bz;
    float a = atan2f(s, c);
    return (c < 0.0f) ? -a : a;
}

// ===== Kernel A: wave-per-node threshold from LDS-staged samples + pos_emb =====
__global__ __launch_bounds__(256) void ka_thresh(
    const float* __restrict__ points, const float* __restrict__ nodes,
    float* __restrict__ tws, int* __restrict__ gcount, float* __restrict__ out)
{
    __shared__ float s3[NSMP * 3];       // 24 KB staged sample points
    const int tid  = threadIdx.x;
    const int w    = tid >> 6;
    const int lane = tid & 63;
    const int bm   = blockIdx.x * 4 + w;
    const int b    = bm >> 10;
    const float* pts = points + (size_t)b * N_PTS * 3;

    {
        const float4* src = (const float4*)pts;
        float4* dst = (float4*)s3;
        #pragma unroll
        for (int k = 0; k < 6; ++k)
            dst[tid + 256 * k] = src[tid + 256 * k];
    }
    __syncthreads();

    const float nx = nodes[(size_t)bm * 3 + 0];
    const float ny = nodes[(size_t)bm * 3 + 1];
    const float nz = nodes[(size_t)bm * 3 + 2];

    unsigned short keys[32];
    #pragma unroll
    for (int s = 0; s < 32; ++s) {
        int j = lane + 64 * s;
        float dx = s3[3 * j + 0] - nx;
        float dy = s3[3 * j + 1] - ny;
        float dz = s3[3 * j + 2] - nz;
        float d2 = dx * dx + dy * dy + dz * dz;
        keys[s] = (unsigned short)(__float_as_uint(d2) >> 16);
    }

    unsigned lo = 0, hi = 0x7F81u, v = 0;
    for (int it = 0; it < 16; ++it) {
        unsigned mid = lo + ((hi - lo) >> 1);
        int c = 0;
        #pragma unroll
        for (int s = 0; s < 32; ++s) c += (int)((unsigned)keys[s] < mid);
        for (int off = 32; off; off >>= 1) c += __shfl_down(c, off);
        c = __shfl(c, 0);
        if (c >= WLO && c <= WHI) { v = mid; break; }
        if (c < WLO) lo = mid; else hi = mid;
        if (hi - lo <= 1u) break;
    }
    if (v == 0) v = hi;
    if (lane == 0) { tws[bm] = __uint_as_float(v << 16); gcount[bm] = 0; }

    #pragma unroll
    for (int r = 0; r < 4; ++r) {
        int d = lane + 64 * r;
        float pv = 0.0f;
        if (d < 3 * NPF) {
            int c2 = d / NPF, rr = d - c2 * NPF, i = rr >> 1;
            float nc = (c2 == 0) ? nx : ((c2 == 1) ? ny : nz);
            const float L2_10000 = 13.287712379549449f;
            float tinv = exp2f(-L2_10000 * (float)i / 42.0f);
            float x = nc * tinv;
            pv = (rr & 1) ? cosf(x) : sinf(x);
        }
        out[(size_t)NNODE * D_MODEL + (size_t)bm * D_MODEL + d] = pv;
    }
}

// ===== Kernel B: mask-matrix scan + wave compaction (no LDS atomics) =====
__global__ __launch_bounds__(256) void kb_scan(
    const float* __restrict__ points, const float* __restrict__ nodes,
    const float* __restrict__ tws, int* __restrict__ gcount,
    unsigned short* __restrict__ cand)
{
    __shared__ unsigned char smask[TN][256];   // 8 KB survivor masks

    const int tile = blockIdx.x;          // 0..127
    const int ch   = blockIdx.y;          // 0..9
    const int ngb  = tile * TN;
    const int b    = ngb >> 10;
    const int tid  = threadIdx.x;
    const float* pts = points + (size_t)b * N_PTS * 3;

    // 8 contiguous points per thread; N_PTS % 8 == 0 -> all-or-nothing per thread
    const int j0 = ch * KB_CHUNK + tid * KB_PPT;
    float px[KB_PPT], py[KB_PPT], pz[KB_PPT], pp[KB_PPT];
    if (j0 < N_PTS) {
        const float4* s4 = (const float4*)(pts + (size_t)j0 * 3);
        float4 v0 = s4[0], v1 = s4[1], v2 = s4[2], v3 = s4[3], v4 = s4[4], v5 = s4[5];
        px[0]=v0.x; py[0]=v0.y; pz[0]=v0.z;
        px[1]=v0.w; py[1]=v1.x; pz[1]=v1.y;
        px[2]=v1.z; py[2]=v1.w; pz[2]=v2.x;
        px[3]=v2.y; py[3]=v2.z; pz[3]=v2.w;
        px[4]=v3.x; py[4]=v3.y; pz[4]=v3.z;
        px[5]=v3.w; py[5]=v4.x; pz[5]=v4.y;
        px[6]=v4.z; py[6]=v4.w; pz[6]=v5.x;
        px[7]=v5.y; py[7]=v5.z; pz[7]=v5.w;
    } else {
        #pragma unroll
        for (int p = 0; p < KB_PPT; ++p) { px[p]=1e18f; py[p]=1e18f; pz[p]=1e18f; }
    }
    #pragma unroll
    for (int p = 0; p < KB_PPT; ++p)
        pp[p] = px[p]*px[p] + py[p]*py[p] + pz[p]*pz[p];

    // Phase 1: masks for all 32 nodes (4-node register groups)
    for (int n0 = 0; n0 < TN; n0 += 4) {
        float ax[4], ay[4], az[4], rhs[4];
        #pragma unroll
        for (int g = 0; g < 4; ++g) {
            int ng = ngb + n0 + g;                       // block-uniform -> s_load
            float nx = nodes[ng * 3 + 0];
            float ny = nodes[ng * 3 + 1];
            float nz = nodes[ng * 3 + 2];
            float t  = tws[ng];
            ax[g] = -2.0f * nx; ay[g] = -2.0f * ny; az[g] = -2.0f * nz;
            // conservative margin >> fma-contraction rounding; kc re-ranks exactly
            rhs[g] = t * 1.0001f + 3e-5f - (nx*nx + ny*ny + nz*nz);
        }
        unsigned msk[4] = {0u, 0u, 0u, 0u};
        #pragma unroll
        for (int p = 0; p < KB_PPT; ++p) {
            #pragma unroll
            for (int g = 0; g < 4; ++g) {
                float s = fmaf(px[p], ax[g], fmaf(py[p], ay[g], fmaf(pz[p], az[g], pp[p])));
                msk[g] |= (s < rhs[g]) ? (1u << p) : 0u;
            }
        }
        #pragma unroll
        for (int g = 0; g < 4; ++g)
            smask[n0 + g][tid] = (unsigned char)msk[g];
    }
    __syncthreads();

    // Phase 2: wave wv compacts its 8 nodes (one global atomic per node)
    const int wv = tid >> 6, lane = tid & 63;
    #pragma unroll
    for (int nn2 = 0; nn2 < TN / 4; ++nn2) {
        int n = wv * (TN / 4) + nn2;
        unsigned long long wmask = 0;
        if (lane < 32) wmask = ((const unsigned long long*)smask[n])[lane];
        int c = (int)__popcll(wmask);
        int inc = c;
        #pragma unroll
        for (int s = 1; s < 32; s <<= 1) {
            int u = __shfl_up(inc, s);
            if (lane >= s) inc += u;
        }
        int total = __shfl(inc, 31);
        if (total == 0) continue;
        int basep = 0;
        if (lane == 0) basep = atomicAdd(&gcount[ngb + n], total);
        basep = __shfl(basep, 0);
        int pos = basep + inc - c;
        while (wmask) {
            int bit = (int)__builtin_ctzll(wmask);
            wmask &= wmask - 1;
            if (pos < CAP)
                cand[(size_t)(ngb + n) * CAP + pos] =
                    (unsigned short)(ch * KB_CHUNK + lane * 64 + bit);
            ++pos;
        }
    }
}

// ===== Kernel C: wave-per-node exact top-50 + PPF features + projection =====
__global__ __launch_bounds__(256) void kc_select(
    const float* __restrict__ points, const float* __restrict__ nodes,
    const float* __restrict__ pnrm, const float* __restrict__ nnrm,
    const float* __restrict__ W, const float* __restrict__ bias,
    const float* __restrict__ tws, const int* __restrict__ gcount,
    const unsigned short* __restrict__ cand, float* __restrict__ out)
{
    __shared__ unsigned long long skeys[4][CAP];   // 24.6 KB
    __shared__ float4 f4v[4][K_NN];
    __shared__ unsigned short selidx[4][K_NN];

    const int tid  = threadIdx.x;
    const int wv   = tid >> 6;
    const int lane = tid & 63;
    const int bm   = blockIdx.x * 4 + wv;
    const int b    = bm >> 10;
    const float* pts = points + (size_t)b * N_PTS * 3;
    const float* pnr = pnrm   + (size_t)b * N_PTS * 3;
    const float nx  = nodes[(size_t)bm * 3 + 0];
    const float ny  = nodes[(size_t)bm * 3 + 1];
    const float nz  = nodes[(size_t)bm * 3 + 2];
    const float n1x = nnrm[(size_t)bm * 3 + 0];
    const float n1y = nnrm[(size_t)bm * 3 + 1];
    const float n1z = nnrm[(size_t)bm * 3 + 2];

    auto d2bits = [&](int i) -> unsigned int {
        float dx = pts[i * 3 + 0] - nx;
        float dy = pts[i * 3 + 1] - ny;
        float dz = pts[i * 3 + 2] - nz;
        return __float_as_uint(dx * dx + dy * dy + dz * dz);
    };

    if (lane < K_NN) selidx[wv][lane] = 0;   // defense vs pathological ties

    const unsigned long long INVALID = ~0ull;
    int cnt = gcount[bm];
    int nsel = 0;

    if (cnt >= K_NN && cnt <= CAP) {
        // ---- fast path: candidate keys in registers, ballot-count refine ----
        const unsigned short* cp = cand + (size_t)bm * CAP;
        unsigned long long key[12];
        #pragma unroll
        for (int r = 0; r < 12; ++r) {
            int s = r * 64 + lane;
            key[r] = INVALID;
            if (s < cnt) {
                int i = (int)cp[s];
                key[r] = ((unsigned long long)d2bits(i) << 32) | (unsigned int)i;
            }
        }

        unsigned long long tcut = INVALID;   // take-all if cnt small or no converge
        bool conv = (cnt <= SELWIN);
        if (!conv) {
            unsigned lo = 0, hi = __float_as_uint(tws[bm]);
            for (int it = 0; it < 32 && !conv; ++it) {
                unsigned mid = lo + ((hi - lo) >> 1);
                unsigned long long tm = (unsigned long long)mid << 32;
                int c = 0;
                #pragma unroll
                for (int r = 0; r < 12; ++r)
                    c += (int)__popcll(__ballot(key[r] < tm));
                if (c >= K_NN && c <= SELWIN) { tcut = tm; conv = true; }
                else if (c < K_NN) lo = mid;
                else hi = mid;
                if (hi - lo <= 1u) break;
            }
        }

        int run = 0;
        #pragma unroll
        for (int r = 0; r < 12; ++r) {
            bool p = key[r] < tcut;
            unsigned long long mask = __ballot(p);
            if (p) {
                int q = run + (int)__popcll(mask & ((1ull << lane) - 1ull));
                skeys[wv][q] = key[r];
            }
            run += (int)__popcll(mask);
        }
        nsel = run;
    } else {
        // ---- slow path (rare): wave-local global repair ----
        unsigned tb = __float_as_uint(tws[bm]);
        unsigned lo = 0, hi = 0x7F000000u, good = 0;
        bool haveLo = false, haveHi = false;
        if (cnt < K_NN) { lo = tb; haveLo = true; }
        else            { hi = tb; haveHi = true; }
        unsigned cur = tb;
        for (int a = 0; a < 40 && !good; ++a) {
            if (haveLo && !haveHi) {
                cur = (cur < 0x7E800000u) ? cur + 0x00800000u : 0x7F000000u;
            } else if (haveHi && !haveLo) {
                cur = (cur >= 0x00800000u) ? cur - 0x00800000u : (cur >> 1);
            } else {
                cur = lo + ((hi - lo) >> 1);
                if (hi - lo <= 1u) { good = hi; break; }
            }
            float tf = __uint_as_float(cur);
            int c = 0;
            for (int i0 = lane; i0 < N_PTS; i0 += 64) {
                float dx = pts[i0 * 3 + 0] - nx;
                float dy = pts[i0 * 3 + 1] - ny;
                float dz = pts[i0 * 3 + 2] - nz;
                c += (int)(dx * dx + dy * dy + dz * dz < tf);
            }
            for (int off = 32; off; off >>= 1) c += __shfl_down(c, off);
            c = __shfl(c, 0);
            if (c >= K_NN && c <= CAP) good = cur;
            else if (c < K_NN) { lo = cur; haveLo = true; }
            else               { hi = cur; haveHi = true; }
        }
        if (!good) good = haveHi ? hi : 0x7F000000u;
        int run = 0;
        for (int base = 0; base < N_PTS; base += 64) {
            int i0 = base + lane;
            bool pred = false;
            unsigned kb2 = 0;
            if (i0 < N_PTS) { kb2 = d2bits(i0); pred = kb2 < good; }
            unsigned long long mask = __ballot(pred);
            if (pred) {
                int q = run + (int)__popcll(mask & ((1ull << lane) - 1ull));
                if (q < CAP)
                    skeys[wv][q] = ((unsigned long long)kb2 << 32) | (unsigned int)i0;
            }
            run += (int)__popcll(mask);
        }
        nsel = run < CAP ? run : CAP;
    }
    __syncthreads();

    // ---- exact rank selection of the 50 nearest (ties -> low idx) ----
    for (int s = lane; s < nsel; s += 64) {
        unsigned long long mk = skeys[wv][s];
        int rank = 0;
        for (int j = 0; j < nsel; ++j) rank += (int)(skeys[wv][j] < mk);
        if (rank < K_NN) selidx[wv][rank] = (unsigned short)mk;  // idx < 65536
    }
    __syncthreads();

    // ---- PPF features (one neighbor per lane) ----
    if (lane < K_NN) {
        int i = (int)selidx[wv][lane];
        float pxx = pts[i * 3 + 0], pyy = pts[i * 3 + 1], pzz = pts[i * 3 + 2];
        float qx = pnr[i * 3 + 0], qy = pnr[i * 3 + 1], qz = pnr[i * 3 + 2];
        float ijx = pxx - nx, ijy = pyy - ny, ijz = pzz - nz;
        float d = sqrtf(ijx * ijx + ijy * ijy + ijz * ijz);
        f4v[wv][lane] = make_float4(d,
                                    signed_angle(ijx, ijy, ijz, n1x, n1y, n1z),
                                    signed_angle(-ijx, -ijy, -ijz, qx, qy, qz),
                                    signed_angle(n1x, n1y, n1z, qx, qy, qz));
    }
    __syncthreads();

    // ---- glob[d] = max_k (f4[k] . W[:,d]) + b[d] ; 4 dims per lane ----
    {
        float w0[4], w1[4], w2[4], w3[4], bb[4], mx[4];
        #pragma unroll
        for (int q = 0; q < 4; ++q) {
            int d = lane + 64 * q;
            w0[q] = W[d]; w1[q] = W[D_MODEL + d];
            w2[q] = W[2 * D_MODEL + d]; w3[q] = W[3 * D_MODEL + d];
            bb[q] = bias[d]; mx[q] = -INFINITY;
        }
        #pragma unroll 5
        for (int k = 0; k < K_NN; ++k) {
            float4 f = f4v[wv][k];
            #pragma unroll
            for (int q = 0; q < 4; ++q)
                mx[q] = fmaxf(mx[q], f.x * w0[q] + f.y * w1[q] + f.z * w2[q] + f.w * w3[q]);
        }
        #pragma unroll
        for (int q = 0; q < 4; ++q)
            out[(size_t)bm * D_MODEL + lane + 64 * q] = mx[q] + bb[q];
    }
}

extern "C" void kernel_launch(void* const* d_in, const int* in_sizes, int n_in,
                              void* d_out, int out_size, void* d_ws, size_t ws_size,
                              hipStream_t stream) {
    const float* points = (const float*)d_in[0];
    const float* nodes  = (const float*)d_in[1];
    const float* pn     = (const float*)d_in[2];
    const float* nn     = (const float*)d_in[3];
    const float* W      = (const float*)d_in[4];
    const float* bias   = (const float*)d_in[5];
    float* out = (float*)d_out;

    // ws layout: tws f32[4096] @0 ; gcount i32[4096] @16K ; cand u16[4096*768] @32K
    char* ws = (char*)d_ws;
    float* tws = (float*)ws;
    int* gcount = (int*)(ws + 16384);
    unsigned short* cand = (unsigned short*)(ws + 32768);

    ka_thresh<<<dim3(NNODE / 4), dim3(256), 0, stream>>>(points, nodes, tws, gcount, out);
    kb_scan<<<dim3(NNODE / TN, KB_NCHUNK), dim3(256), 0, stream>>>(points, nodes, tws, gcount, cand);
    kc_select<<<dim3(NNODE / 4), dim3(256), 0, stream>>>(points, nodes, pn, nn, W, bias,
                                                         tws, gcount, cand, out);
}